// Round 5
// baseline (174.619 us; speedup 1.0000x reference)
//
#include <hip/hip_runtime.h>
#include <math.h>

// ---------------- problem constants ----------------
#define N_TOTAL 2097024
#define HWF (1024 * 1536)

#define OFF0 0
#define OFF1 1572864
#define OFF2 1966080
#define OFF3 2064384
#define OFF4 2088960
#define OFF5 2095104
#define OFF6 2096640

// output section offsets (floats)
#define OUT_LS   (3 * HWF)
#define OUT_DEC  (6 * HWF)
#define OUT_RATE (9 * HWF)

// vector types; aligned(4) so they can load at any dword offset
typedef float f4  __attribute__((ext_vector_type(4), aligned(4)));
typedef float pf2 __attribute__((ext_vector_type(2), aligned(4)));

__device__ __forceinline__ pf2 splat2(float s) { return (pf2){s, s}; }
__device__ __forceinline__ pf2 pk_fma(pf2 a, pf2 b, pf2 c) { return __builtin_elementwise_fma(a, b, c); }
__device__ __forceinline__ pf2 pk_max(pf2 a, pf2 b) { return __builtin_elementwise_max(a, b); }
__device__ __forceinline__ pf2 pk_min(pf2 a, pf2 b) { return __builtin_elementwise_min(a, b); }

// ---------------- softround (fast tanh via v_exp + v_rcp) ----------------
__device__ __forceinline__ float softround_f(float x) {
    const float INV_T = 1.0f / 0.3f;
    const float HALF_OVER_TANH = 0.53699381f; // 0.5 / tanh(0.5/0.3)
    float fl = floorf(x);
    float z = (x - fl - 0.5f) * INV_T;        // z in [-1.667, 1.667]
    float e = __expf(2.0f * z);               // v_exp_f32
    float th = 1.0f - 2.0f * __builtin_amdgcn_rcpf(e + 1.0f);
    return fl + th * HALF_OVER_TANH + 0.5f;
}

// ---------------- kernel 1: quantization ----------------
__global__ void quant_kernel(const float* __restrict__ l0, const float* __restrict__ l1,
                             const float* __restrict__ l2, const float* __restrict__ l3,
                             const float* __restrict__ l4, const float* __restrict__ l5,
                             const float* __restrict__ l6, const float* __restrict__ noise,
                             float* __restrict__ flat_q) {
    int idx = blockIdx.x * blockDim.x + threadIdx.x;
    if (idx >= N_TOTAL) return;
    float v;
    if      (idx < OFF1) v = l0[idx - OFF0];
    else if (idx < OFF2) v = l1[idx - OFF1];
    else if (idx < OFF3) v = l2[idx - OFF2];
    else if (idx < OFF4) v = l3[idx - OFF3];
    else if (idx < OFF5) v = l4[idx - OFF4];
    else if (idx < OFF6) v = l5[idx - OFF5];
    else                 v = l6[idx - OFF6];
    float x = v * 16.0f;                       // GAIN
    float s1 = softround_f(x);
    float s2 = softround_f(s1 + noise[idx] - 0.5f);
    flat_q[idx] = s2;
}

// ---------------- kernel 2: fused ARM over all 7 grids, 2 px/thread, packed f32 ----------------
template <int H, int W, int OFFT>
__device__ __forceinline__ void arm_body2(const float* __restrict__ flat_q, int pair,
                                          const float* __restrict__ w1, const float* __restrict__ b1,
                                          const float* __restrict__ w2, const float* __restrict__ b2,
                                          const float* __restrict__ wo, const float* __restrict__ bo,
                                          float* __restrict__ rate_out) {
    constexpr int NPAIR = H * W / 2;
    if (pair >= NPAIR) return;
    int pos = 2 * pair;
    int y = (unsigned)pos / (unsigned)W;
    int x = pos - y * W;
    const float* g = flat_q + OFFT;

    const int DY[16] = {-3,-3,-3,-2,-2,-2,-2,-2,-1,-1,-1,-1,-1,-1, 0, 0};
    const int DX[16] = {-1, 0, 1,-2,-1, 0, 1, 2,-3,-2,-1, 0, 1, 2,-2,-1};
    pf2 ctx[16];
    bool interior = (y >= 3) && (x >= 3) && (x <= W - 4);
    if (interior) {
#pragma unroll
        for (int k = 0; k < 16; k++)
            ctx[k] = *(const pf2*)&g[(y + DY[k]) * W + x + DX[k]];
    } else {
#pragma unroll
        for (int k = 0; k < 16; k++) {
            int yy = y + DY[k];
            float lo = 0.0f, hi = 0.0f;
            if (yy >= 0) {
                int xx = x + DX[k];
                if (xx >= 0 && xx < W)          lo = g[yy * W + xx];
                if (xx + 1 >= 0 && xx + 1 < W)  hi = g[yy * W + xx + 1];
            }
            ctx[k] = (pf2){lo, hi};
        }
    }

    pf2 h1[16];
#pragma unroll 4
    for (int j = 0; j < 16; j++) {
        pf2 acc = splat2(b1[j]) + ctx[j];
#pragma unroll
        for (int k = 0; k < 16; k++) acc = pk_fma(splat2(w1[j * 16 + k]), ctx[k], acc);
        h1[j] = pk_max(acc, splat2(0.0f));
    }
    pf2 h2[16];
#pragma unroll 4
    for (int j = 0; j < 16; j++) {
        pf2 acc = splat2(b2[j]) + h1[j];
#pragma unroll
        for (int k = 0; k < 16; k++) acc = pk_fma(splat2(w2[j * 16 + k]), h1[k], acc);
        h2[j] = pk_max(acc, splat2(0.0f));
    }
    pf2 mu = splat2(bo[0]), ls = splat2(bo[1]);
#pragma unroll
    for (int k = 0; k < 16; k++) {
        mu = pk_fma(splat2(wo[k]), h2[k], mu);
        ls = pk_fma(splat2(wo[16 + k]), h2[k], ls);
    }

    pf2 q = *(const pf2*)&g[pos];
    pf2 rate;
#pragma unroll
    for (int c = 0; c < 2; c++) {
        float lsc = fminf(fmaxf(ls[c], -13.8155f), 13.8155f);
        float inv_scale = __expf(0.5f * lsc);
        float da = (q[c] + 0.5f) - mu[c];
        float db = (q[c] - 0.5f) - mu[c];
        float la = 0.5f - 0.5f * copysignf(1.0f, da) * expm1f(-fabsf(da) * inv_scale);
        float lb = 0.5f - 0.5f * copysignf(1.0f, db) * expm1f(-fabsf(db) * inv_scale);
        float proba = fmaxf(la - lb, 1.52587890625e-05f);
        rate[c] = -log2f(proba);
    }
    *(pf2*)&rate_out[OFFT + pos] = rate;
}

// per-grid pair-blocks (256 pairs/block): g0:3072 g1:768 g2:192 g3:48 g4:12 g5:3 g6:1
// cum: 3072, 3840, 4032, 4080, 4092, 4095, 4096
__global__ __launch_bounds__(256) void arm_all_kernel(
    const float* __restrict__ flat_q,
    const float* __restrict__ w1, const float* __restrict__ b1,
    const float* __restrict__ w2, const float* __restrict__ b2,
    const float* __restrict__ wo, const float* __restrict__ bo,
    float* __restrict__ rate_out) {
    int b = blockIdx.x;
    int t = threadIdx.x;
    if (b < 3072) {
        arm_body2<1024, 1536, OFF0>(flat_q, b * 256 + t, w1, b1, w2, b2, wo, bo, rate_out);
    } else if (b < 3840) {
        arm_body2<512, 768, OFF1>(flat_q, (b - 3072) * 256 + t, w1, b1, w2, b2, wo, bo, rate_out);
    } else if (b < 4032) {
        arm_body2<256, 384, OFF2>(flat_q, (b - 3840) * 256 + t, w1, b1, w2, b2, wo, bo, rate_out);
    } else if (b < 4080) {
        arm_body2<128, 192, OFF3>(flat_q, (b - 4032) * 256 + t, w1, b1, w2, b2, wo, bo, rate_out);
    } else if (b < 4092) {
        arm_body2<64, 96, OFF4>(flat_q, (b - 4080) * 256 + t, w1, b1, w2, b2, wo, bo, rate_out);
    } else if (b < 4095) {
        arm_body2<32, 48, OFF5>(flat_q, (b - 4092) * 256 + t, w1, b1, w2, b2, wo, bo, rate_out);
    } else {
        arm_body2<16, 24, OFF6>(flat_q, (b - 4095) * 256 + t, w1, b1, w2, b2, wo, bo, rate_out);
    }
}

// ---------------- packed quad helpers ----------------
// up: o01 = {(2i,2j),(2i,2j+1)}, o23 = {(2i+1,2j),(2i+1,2j+1)}
__device__ __forceinline__ void up_quad_pk(const float* __restrict__ in, int H, int W,
                                           int i, int j, const float* K, pf2& o01, pf2& o23) {
    float w[5][5];
    bool interior = (i >= 2 && i <= H - 3 && j >= 2 && j <= W - 3);
    if (interior) {
        const float* p = in + (i - 2) * W + (j - 2);
#pragma unroll
        for (int r = 0; r < 5; r++) {
            f4 a = *(const f4*)p;
            w[r][0] = a.x; w[r][1] = a.y; w[r][2] = a.z; w[r][3] = a.w;
            w[r][4] = p[4];
            p += W;
        }
    } else {
#pragma unroll
        for (int r = 0; r < 5; r++)
#pragma unroll
            for (int e = 0; e < 5; e++) {
                int yy = i - 2 + r, xx = j - 2 + e;
                w[r][e] = (yy >= 0 && yy < H && xx >= 0 && xx < W) ? in[yy * W + xx] : 0.0f;
            }
    }
    // h01[r] = {even-col, odd-col} horizontal results
    pf2 h01[5];
#pragma unroll
    for (int r = 0; r < 5; r++) {
        pf2 acc = splat2(0.0f);
#pragma unroll
        for (int e = 0; e < 4; e++)
            acc = pk_fma((pf2){K[2 * e], K[2 * e + 1]}, (pf2){w[r][e], w[r][e + 1]}, acc);
        h01[r] = acc;
    }
    o01 = splat2(0.0f); o23 = splat2(0.0f);
#pragma unroll
    for (int d = 0; d < 4; d++) {
        o01 = pk_fma(splat2(K[2 * d]),     h01[d],     o01);
        o23 = pk_fma(splat2(K[2 * d + 1]), h01[d + 1], o23);
    }
}

__device__ __forceinline__ void conv7_quad_pk(const float* __restrict__ dec, int H, int W,
                                              int i, int j, const float* k, pf2& o01, pf2& o23) {
    int Y = 2 * i, X = 2 * j;
    pf2 g01[8];
    bool interior = (Y - 3 >= 0 && Y + 4 <= H - 1 && X - 3 >= 0 && X + 4 <= W - 1);
#pragma unroll
    for (int r = 0; r < 8; r++) {
        float wv[8];
        if (interior) {
            const float* p = dec + (Y - 3 + r) * W + (X - 3);
            f4 a = *(const f4*)p;
            f4 b = *(const f4*)(p + 4);
            wv[0] = a.x; wv[1] = a.y; wv[2] = a.z; wv[3] = a.w;
            wv[4] = b.x; wv[5] = b.y; wv[6] = b.z; wv[7] = b.w;
        } else {
#pragma unroll
            for (int q = 0; q < 8; q++) {
                int yy = Y - 3 + r, xx = X - 3 + q;
                wv[q] = (yy >= 0 && yy < H && xx >= 0 && xx < W) ? dec[yy * W + xx] : 0.0f;
            }
        }
        pf2 acc = splat2(0.0f);
#pragma unroll
        for (int q = 0; q < 7; q++)
            acc = pk_fma(splat2(k[q]), (pf2){wv[q], wv[q + 1]}, acc);
        g01[r] = acc;
    }
    o01 = splat2(0.0f); o23 = splat2(0.0f);
#pragma unroll
    for (int r = 0; r < 7; r++) {
        o01 = pk_fma(splat2(k[r]), g01[r],     o01);
        o23 = pk_fma(splat2(k[r]), g01[r + 1], o23);
    }
}

// ---------------- kernel 3: intermediate pyramid step (packed quad per thread) ----------------
__global__ void pyramid_quad_kernel(const float* __restrict__ xin, int hin, int win_,
                                    const float* __restrict__ dec,
                                    const float* __restrict__ upsk, const float* __restrict__ prek,
                                    float* __restrict__ xout, int hout, int wout) {
    int qw = wout >> 1, qh = hout >> 1;
    int j = blockIdx.x * blockDim.x + threadIdx.x;
    int i = blockIdx.y * blockDim.y + threadIdx.y;
    int c = blockIdx.z;
    if (j >= qw || i >= qh) return;
    pf2 o01, o23;
    if (c == 0) {
        float k[7];
#pragma unroll
        for (int p = 0; p < 7; p++) k[p] = prek[p];
        conv7_quad_pk(dec, hout, wout, i, j, k, o01, o23);
    } else {
        float K[8];
#pragma unroll
        for (int p = 0; p < 8; p++) K[p] = upsk[p];
        up_quad_pk(xin + (size_t)(c - 1) * hin * win_, hin, win_, i, j, K, o01, o23);
    }
    size_t base = ((size_t)c * hout + 2 * i) * wout + 2 * j;
    *(pf2*)(xout + base)        = o01;
    *(pf2*)(xout + base + wout) = o23;
}

// ---------------- kernel 4: fused final pyramid step + synthesis (packed f32) ----------------
__global__ __launch_bounds__(256) void final_kernel(
    const float* __restrict__ up_in,  // 6 ch @ 512x768
    const float* __restrict__ dec0,   // 1024x1536
    const float* __restrict__ upsk, const float* __restrict__ prek,
    const float* __restrict__ w1, const float* __restrict__ b1,
    const float* __restrict__ w2, const float* __restrict__ b2,
    float* __restrict__ out) {
    const int H2_ = 512, W2_ = 768, H1_ = 1024, W1_ = 1536;
    int t = threadIdx.x;
    int j = blockIdx.x * 16 + (t & 15);   // quad col, [0,768)
    int i = blockIdx.y * 16 + (t >> 4);   // quad row, [0,512)

    float K[8], kp[7];
#pragma unroll
    for (int p = 0; p < 8; p++) K[p] = upsk[p];
#pragma unroll
    for (int p = 0; p < 7; p++) kp[p] = prek[p];

    pf2 px01[7], px23[7];
    conv7_quad_pk(dec0, H1_, W1_, i, j, kp, px01[0], px23[0]);
#pragma unroll
    for (int c = 0; c < 6; c++)
        up_quad_pk(up_in + (size_t)c * (H2_ * W2_), H2_, W2_, i, j, K, px01[c + 1], px23[c + 1]);

    // synthesis MLP, packed: (px0,px1) and (px2,px3) lanes
    pf2 o01[6], o23[6];
#pragma unroll
    for (int q = 0; q < 6; q++) { o01[q] = splat2(b2[q]); o23[q] = splat2(b2[q]); }
#pragma unroll 4
    for (int k = 0; k < 48; k++) {
        pf2 a01 = splat2(b1[k]), a23 = a01;
#pragma unroll
        for (int c = 0; c < 7; c++) {
            pf2 wk = splat2(w1[k * 7 + c]);
            a01 = pk_fma(wk, px01[c], a01);
            a23 = pk_fma(wk, px23[c], a23);
        }
        a01 = pk_max(a01, splat2(0.0f));
        a23 = pk_max(a23, splat2(0.0f));
#pragma unroll
        for (int q = 0; q < 6; q++) {
            pf2 wj = splat2(w2[q * 48 + k]);
            o01[q] = pk_fma(wj, a01, o01[q]);
            o23[q] = pk_fma(wj, a23, o23[q]);
        }
    }

    size_t base = (size_t)(2 * i) * W1_ + 2 * j;
#pragma unroll
    for (int c = 0; c < 3; c++) {
        *(pf2*)(out + (size_t)c * HWF + base)       = o01[c];
        *(pf2*)(out + (size_t)c * HWF + base + W1_) = o23[c];
        *(pf2*)(out + OUT_LS + (size_t)c * HWF + base)       = o01[c + 3];
        *(pf2*)(out + OUT_LS + (size_t)c * HWF + base + W1_) = o23[c + 3];
        *(pf2*)(out + OUT_DEC + (size_t)c * HWF + base) =
            pk_min(pk_max(o01[c], splat2(0.0f)), splat2(1.0f));
        *(pf2*)(out + OUT_DEC + (size_t)c * HWF + base + W1_) =
            pk_min(pk_max(o23[c], splat2(0.0f)), splat2(1.0f));
    }
}

// ---------------- launch ----------------
extern "C" void kernel_launch(void* const* d_in, const int* in_sizes, int n_in,
                              void* d_out, int out_size, void* d_ws, size_t ws_size,
                              hipStream_t stream) {
    const float* lat[7];
    for (int i = 0; i < 7; i++) lat[i] = (const float*)d_in[i];
    const float* noise  = (const float*)d_in[7];
    const float* arm_w1 = (const float*)d_in[8];
    const float* arm_b1 = (const float*)d_in[9];
    const float* arm_w2 = (const float*)d_in[10];
    const float* arm_b2 = (const float*)d_in[11];
    const float* arm_wo = (const float*)d_in[12];
    const float* arm_bo = (const float*)d_in[13];
    const float* ups_k  = (const float*)d_in[14]; // (6,8)
    const float* pre_k  = (const float*)d_in[15]; // (6,7)
    const float* syn_w1 = (const float*)d_in[16]; // (48,7)
    const float* syn_b1 = (const float*)d_in[17];
    const float* syn_w2 = (const float*)d_in[18]; // (6,48)
    const float* syn_b2 = (const float*)d_in[19];
    float* out = (float*)d_out;

    float* flat_q = (float*)d_ws;                 // N_TOTAL
    float* bufA   = flat_q + N_TOTAL;             // up to 6*512*768
    float* bufB   = bufA + 6 * 512 * 768;         // up to 5*256*384

    static const int SH[7]  = {1024, 512, 256, 128, 64, 32, 16};
    static const int SW[7]  = {1536, 768, 384, 192, 96, 48, 24};
    static const int OFF[7] = {OFF0, OFF1, OFF2, OFF3, OFF4, OFF5, OFF6};

    // 1. quantization
    quant_kernel<<<(N_TOTAL + 255) / 256, 256, 0, stream>>>(
        lat[0], lat[1], lat[2], lat[3], lat[4], lat[5], lat[6], noise, flat_q);

    // 2. fused ARM + rate (all 7 grids, one launch, 2 px/thread)
    arm_all_kernel<<<4096, 256, 0, stream>>>(flat_q, arm_w1, arm_b1, arm_w2, arm_b2,
                                             arm_wo, arm_bo, out + OUT_RATE);

    // 3. intermediate pyramid steps s=0..4 (quad kernels), ping-pong bufA/bufB
    const float* xin = flat_q + OFF6; // dec[6], 1ch 16x24
    float* bufs[2] = {bufA, bufB};
    for (int s = 0; s < 5; s++) {
        int i    = 6 - s;
        int hin  = SH[i], win_ = SW[i];
        int hout = SH[i - 1], wout = SW[i - 1];
        int cin  = s + 1;
        float* xout = bufs[s & 1];
        dim3 blk(16, 16);
        dim3 grd((wout / 2 + 15) / 16, (hout / 2 + 15) / 16, cin + 1);
        pyramid_quad_kernel<<<grd, blk, 0, stream>>>(xin, hin, win_,
                                                     flat_q + OFF[i - 1],
                                                     ups_k + s * 8, pre_k + s * 7,
                                                     xout, hout, wout);
        xin = xout;
    }

    // 4. fused final step + synthesis
    dim3 fgrd(768 / 16, 512 / 16);
    final_kernel<<<fgrd, 256, 0, stream>>>(bufA, flat_q,
                                           ups_k + 5 * 8, pre_k + 5 * 7,
                                           syn_w1, syn_b1, syn_w2, syn_b2, out);
}

// Round 6
// 169.914 us; speedup vs baseline: 1.0277x; 1.0277x over previous
//
#include <hip/hip_runtime.h>
#include <math.h>

// ---------------- problem constants ----------------
#define N_TOTAL 2097024
#define HWF (1024 * 1536)

#define OFF0 0
#define OFF1 1572864
#define OFF2 1966080
#define OFF3 2064384
#define OFF4 2088960
#define OFF5 2095104
#define OFF6 2096640

// output section offsets (floats)
#define OUT_LS   (3 * HWF)
#define OUT_DEC  (6 * HWF)
#define OUT_RATE (9 * HWF)

// float4 with 4-byte alignment (windows are only dword-aligned)
typedef float f4 __attribute__((ext_vector_type(4), aligned(4)));

// ---------------- softround (fast tanh via v_exp + v_rcp) ----------------
__device__ __forceinline__ float softround_f(float x) {
    const float INV_T = 1.0f / 0.3f;
    const float HALF_OVER_TANH = 0.53699381f; // 0.5 / tanh(0.5/0.3)
    float fl = floorf(x);
    float z = (x - fl - 0.5f) * INV_T;
    float e = __expf(2.0f * z);
    float th = 1.0f - 2.0f * __builtin_amdgcn_rcpf(e + 1.0f);
    return fl + th * HALF_OVER_TANH + 0.5f;
}

// ---------------- kernel 1: quantization ----------------
__global__ void quant_kernel(const float* __restrict__ l0, const float* __restrict__ l1,
                             const float* __restrict__ l2, const float* __restrict__ l3,
                             const float* __restrict__ l4, const float* __restrict__ l5,
                             const float* __restrict__ l6, const float* __restrict__ noise,
                             float* __restrict__ flat_q) {
    int idx = blockIdx.x * blockDim.x + threadIdx.x;
    if (idx >= N_TOTAL) return;
    float v;
    if      (idx < OFF1) v = l0[idx - OFF0];
    else if (idx < OFF2) v = l1[idx - OFF1];
    else if (idx < OFF3) v = l2[idx - OFF2];
    else if (idx < OFF4) v = l3[idx - OFF3];
    else if (idx < OFF5) v = l4[idx - OFF4];
    else if (idx < OFF6) v = l5[idx - OFF5];
    else                 v = l6[idx - OFF6];
    float x = v * 16.0f;                       // GAIN
    float s1 = softround_f(x);
    float s2 = softround_f(s1 + noise[idx] - 0.5f);
    flat_q[idx] = s2;
}

// ---------------- ARM body (1 px/thread, scalar weights via constant cache) ----------------
template <int H, int W, int OFFT>
__device__ __forceinline__ void arm_body(const float* __restrict__ flat_q, int pos,
                                         const float* __restrict__ w1, const float* __restrict__ b1,
                                         const float* __restrict__ w2, const float* __restrict__ b2,
                                         const float* __restrict__ wo, const float* __restrict__ bo,
                                         float* __restrict__ rate_out) {
    if (pos >= H * W) return;
    unsigned up = (unsigned)pos;
    int y = up / (unsigned)W;
    int x = pos - y * W;
    const float* g = flat_q + OFFT;

    const int DY[16] = {-3,-3,-3,-2,-2,-2,-2,-2,-1,-1,-1,-1,-1,-1, 0, 0};
    const int DX[16] = {-1, 0, 1,-2,-1, 0, 1, 2,-3,-2,-1, 0, 1, 2,-2,-1};
    float ctx[16];
#pragma unroll
    for (int k = 0; k < 16; k++) {
        int yy = y + DY[k], xx = x + DX[k];
        ctx[k] = (yy >= 0 && yy < H && xx >= 0 && xx < W) ? g[yy * W + xx] : 0.0f;
    }

    float h1[16];
#pragma unroll 4
    for (int j = 0; j < 16; j++) {
        float acc = b1[j] + ctx[j];
#pragma unroll
        for (int k = 0; k < 16; k++) acc = fmaf(w1[j * 16 + k], ctx[k], acc);
        h1[j] = fmaxf(acc, 0.0f);
    }
    float h2[16];
#pragma unroll 4
    for (int j = 0; j < 16; j++) {
        float acc = b2[j] + h1[j];
#pragma unroll
        for (int k = 0; k < 16; k++) acc = fmaf(w2[j * 16 + k], h1[k], acc);
        h2[j] = fmaxf(acc, 0.0f);
    }
    float mu = bo[0], ls = bo[1];
#pragma unroll
    for (int k = 0; k < 16; k++) {
        mu = fmaf(wo[k], h2[k], mu);
        ls = fmaf(wo[16 + k], h2[k], ls);
    }
    ls = fminf(fmaxf(ls, -13.8155f), 13.8155f);
    float inv_scale = __expf(0.5f * ls * 1.44269504f * 0.69314718f); // keep expf semantics
    // (expf(0.5*ls)) -- write plainly:
    inv_scale = expf(0.5f * ls);

    float q = g[(size_t)y * W + x];
    float da = (q + 0.5f) - mu;
    float db = (q - 0.5f) - mu;
    float la = 0.5f - 0.5f * copysignf(1.0f, da) * expm1f(-fabsf(da) * inv_scale);
    float lb = 0.5f - 0.5f * copysignf(1.0f, db) * expm1f(-fabsf(db) * inv_scale);
    float proba = fmaxf(la - lb, 1.52587890625e-05f);
    rate_out[OFFT + pos] = -log2f(proba);
}

// ---------------- quad helpers (separable, register-resident) ----------------
__device__ __forceinline__ void up_quad(const float* __restrict__ in, int H, int W,
                                        int i, int j, const float* K, float o[4]) {
    float w[5][5];
    bool interior = (i >= 2 && i <= H - 3 && j >= 2 && j <= W - 3);
    if (interior) {
        const float* p = in + (i - 2) * W + (j - 2);
#pragma unroll
        for (int r = 0; r < 5; r++) {
            f4 a = *(const f4*)p;
            w[r][0] = a.x; w[r][1] = a.y; w[r][2] = a.z; w[r][3] = a.w;
            w[r][4] = p[4];
            p += W;
        }
    } else {
#pragma unroll
        for (int r = 0; r < 5; r++)
#pragma unroll
            for (int e = 0; e < 5; e++) {
                int yy = i - 2 + r, xx = j - 2 + e;
                w[r][e] = (yy >= 0 && yy < H && xx >= 0 && xx < W) ? in[yy * W + xx] : 0.0f;
            }
    }
    float h0[5], h1[5];
#pragma unroll
    for (int r = 0; r < 5; r++) {
        h0[r] = K[0]*w[r][0] + K[2]*w[r][1] + K[4]*w[r][2] + K[6]*w[r][3];
        h1[r] = K[1]*w[r][1] + K[3]*w[r][2] + K[5]*w[r][3] + K[7]*w[r][4];
    }
    o[0] = K[0]*h0[0] + K[2]*h0[1] + K[4]*h0[2] + K[6]*h0[3];
    o[1] = K[0]*h1[0] + K[2]*h1[1] + K[4]*h1[2] + K[6]*h1[3];
    o[2] = K[1]*h0[1] + K[3]*h0[2] + K[5]*h0[3] + K[7]*h0[4];
    o[3] = K[1]*h1[1] + K[3]*h1[2] + K[5]*h1[3] + K[7]*h1[4];
}

__device__ __forceinline__ void conv7_quad(const float* __restrict__ dec, int H, int W,
                                           int i, int j, const float* k, float o[4]) {
    int Y = 2 * i, X = 2 * j;
    float g0[8], g1[8];
    bool interior = (Y - 3 >= 0 && Y + 4 <= H - 1 && X - 3 >= 0 && X + 4 <= W - 1);
    if (interior) {
        const float* p = dec + (Y - 3) * W + (X - 3);
#pragma unroll
        for (int r = 0; r < 8; r++) {
            f4 a = *(const f4*)p;
            f4 b = *(const f4*)(p + 4);
            g0[r] = k[0]*a.x + k[1]*a.y + k[2]*a.z + k[3]*a.w + k[4]*b.x + k[5]*b.y + k[6]*b.z;
            g1[r] = k[0]*a.y + k[1]*a.z + k[2]*a.w + k[3]*b.x + k[4]*b.y + k[5]*b.z + k[6]*b.w;
            p += W;
        }
    } else {
#pragma unroll
        for (int r = 0; r < 8; r++) {
            float wv[8];
#pragma unroll
            for (int q = 0; q < 8; q++) {
                int yy = Y - 3 + r, xx = X - 3 + q;
                wv[q] = (yy >= 0 && yy < H && xx >= 0 && xx < W) ? dec[yy * W + xx] : 0.0f;
            }
            g0[r] = k[0]*wv[0] + k[1]*wv[1] + k[2]*wv[2] + k[3]*wv[3] + k[4]*wv[4] + k[5]*wv[5] + k[6]*wv[6];
            g1[r] = k[0]*wv[1] + k[1]*wv[2] + k[2]*wv[3] + k[3]*wv[4] + k[4]*wv[5] + k[5]*wv[6] + k[6]*wv[7];
        }
    }
    o[0] = k[0]*g0[0] + k[1]*g0[1] + k[2]*g0[2] + k[3]*g0[3] + k[4]*g0[4] + k[5]*g0[5] + k[6]*g0[6];
    o[1] = k[0]*g1[0] + k[1]*g1[1] + k[2]*g1[2] + k[3]*g1[3] + k[4]*g1[4] + k[5]*g1[5] + k[6]*g1[6];
    o[2] = k[0]*g0[1] + k[1]*g0[2] + k[2]*g0[3] + k[3]*g0[4] + k[4]*g0[5] + k[5]*g0[6] + k[6]*g0[7];
    o[3] = k[0]*g1[1] + k[1]*g1[2] + k[2]*g1[3] + k[3]*g1[4] + k[4]*g1[5] + k[5]*g1[6] + k[6]*g1[7];
}

// ---------------- kernel 3: intermediate pyramid step (quad per thread) ----------------
__global__ void pyramid_quad_kernel(const float* __restrict__ xin, int hin, int win_,
                                    const float* __restrict__ dec,
                                    const float* __restrict__ upsk, const float* __restrict__ prek,
                                    float* __restrict__ xout, int hout, int wout) {
    int qw = wout >> 1, qh = hout >> 1;
    int j = blockIdx.x * blockDim.x + threadIdx.x;
    int i = blockIdx.y * blockDim.y + threadIdx.y;
    int c = blockIdx.z;
    if (j >= qw || i >= qh) return;
    float o[4];
    if (c == 0) {
        float k[7];
#pragma unroll
        for (int p = 0; p < 7; p++) k[p] = prek[p];
        conv7_quad(dec, hout, wout, i, j, k, o);
    } else {
        float K[8];
#pragma unroll
        for (int p = 0; p < 8; p++) K[p] = upsk[p];
        up_quad(xin + (size_t)(c - 1) * hin * win_, hin, win_, i, j, K, o);
    }
    size_t base = ((size_t)c * hout + 2 * i) * wout + 2 * j;
    *(float2*)(xout + base)        = make_float2(o[0], o[1]);
    *(float2*)(xout + base + wout) = make_float2(o[2], o[3]);
}

// ---------------- final-path body: fused last pyramid step + synthesis ----------------
__device__ __forceinline__ void final_body(int b, int t,
    const float* __restrict__ up_in,  // 6 ch @ 512x768
    const float* __restrict__ dec0,   // 1024x1536
    const float* __restrict__ upsk, const float* __restrict__ prek,
    const float* __restrict__ w1, const float* __restrict__ b1,
    const float* __restrict__ w2, const float* __restrict__ b2,
    float* __restrict__ out) {
    const int H2_ = 512, W2_ = 768, H1_ = 1024, W1_ = 1536;
    unsigned ub = (unsigned)b;
    int by = ub / 48u;               // [0,32)
    int bx = b - by * 48;            // [0,48)
    int j = bx * 16 + (t & 15);      // quad col, [0,768)
    int i = by * 16 + (t >> 4);      // quad row, [0,512)

    float K[8], kp[7];
#pragma unroll
    for (int p = 0; p < 8; p++) K[p] = upsk[p];
#pragma unroll
    for (int p = 0; p < 7; p++) kp[p] = prek[p];

    float px0[7], px1[7], px2[7], px3[7];
    {
        float o[4];
        conv7_quad(dec0, H1_, W1_, i, j, kp, o);
        px0[0] = o[0]; px1[0] = o[1]; px2[0] = o[2]; px3[0] = o[3];
    }
#pragma unroll
    for (int c = 0; c < 6; c++) {
        float o[4];
        up_quad(up_in + (size_t)c * (H2_ * W2_), H2_, W2_, i, j, K, o);
        px0[c + 1] = o[0]; px1[c + 1] = o[1]; px2[c + 1] = o[2]; px3[c + 1] = o[3];
    }

    float o0[6], o1[6], o2[6], o3[6];
#pragma unroll
    for (int q = 0; q < 6; q++) {
        float bq = b2[q];
        o0[q] = bq; o1[q] = bq; o2[q] = bq; o3[q] = bq;
    }
#pragma unroll 4
    for (int k = 0; k < 48; k++) {
        float bk = b1[k];
        float a0 = bk, a1 = bk, a2 = bk, a3 = bk;
#pragma unroll
        for (int c = 0; c < 7; c++) {
            float wk = w1[k * 7 + c];
            a0 = fmaf(wk, px0[c], a0);
            a1 = fmaf(wk, px1[c], a1);
            a2 = fmaf(wk, px2[c], a2);
            a3 = fmaf(wk, px3[c], a3);
        }
        a0 = fmaxf(a0, 0.0f); a1 = fmaxf(a1, 0.0f); a2 = fmaxf(a2, 0.0f); a3 = fmaxf(a3, 0.0f);
#pragma unroll
        for (int q = 0; q < 6; q++) {
            float wj = w2[q * 48 + k];
            o0[q] = fmaf(wj, a0, o0[q]);
            o1[q] = fmaf(wj, a1, o1[q]);
            o2[q] = fmaf(wj, a2, o2[q]);
            o3[q] = fmaf(wj, a3, o3[q]);
        }
    }

    size_t base = (size_t)(2 * i) * W1_ + 2 * j;
#pragma unroll
    for (int c = 0; c < 3; c++) {
        *(float2*)(out + (size_t)c * HWF + base)       = make_float2(o0[c], o1[c]);
        *(float2*)(out + (size_t)c * HWF + base + W1_) = make_float2(o2[c], o3[c]);
        *(float2*)(out + OUT_LS + (size_t)c * HWF + base)       = make_float2(o0[c + 3], o1[c + 3]);
        *(float2*)(out + OUT_LS + (size_t)c * HWF + base + W1_) = make_float2(o2[c + 3], o3[c + 3]);
        *(float2*)(out + OUT_DEC + (size_t)c * HWF + base) =
            make_float2(fminf(fmaxf(o0[c], 0.0f), 1.0f), fminf(fmaxf(o1[c], 0.0f), 1.0f));
        *(float2*)(out + OUT_DEC + (size_t)c * HWF + base + W1_) =
            make_float2(fminf(fmaxf(o2[c], 0.0f), 1.0f), fminf(fmaxf(o3[c], 0.0f), 1.0f));
    }
}

// ---------------- mega kernel: final-path blocks [0,1536) + ARM blocks [1536,9728) ----------------
// ARM block prefix (256 px/block): g0:6144 g1:1536 g2:384 g3:96 g4:24 g5:6 g6:2 -> cum 6144,7680,8064,8160,8184,8190,8192
__global__ __launch_bounds__(256) void mega_kernel(
    const float* __restrict__ up_in, const float* __restrict__ flat_q,
    const float* __restrict__ upsk, const float* __restrict__ prek,
    const float* __restrict__ sw1, const float* __restrict__ sb1,
    const float* __restrict__ sw2, const float* __restrict__ sb2,
    const float* __restrict__ aw1, const float* __restrict__ ab1,
    const float* __restrict__ aw2, const float* __restrict__ ab2,
    const float* __restrict__ awo, const float* __restrict__ abo,
    float* __restrict__ out) {
    int b = blockIdx.x;
    int t = threadIdx.x;
    if (b < 1536) {
        final_body(b, t, up_in, flat_q, upsk, prek, sw1, sb1, sw2, sb2, out);
        return;
    }
    int ab = b - 1536;
    float* rate_out = out + OUT_RATE;
    if (ab < 6144) {
        arm_body<1024, 1536, OFF0>(flat_q, ab * 256 + t, aw1, ab1, aw2, ab2, awo, abo, rate_out);
    } else if (ab < 7680) {
        arm_body<512, 768, OFF1>(flat_q, (ab - 6144) * 256 + t, aw1, ab1, aw2, ab2, awo, abo, rate_out);
    } else if (ab < 8064) {
        arm_body<256, 384, OFF2>(flat_q, (ab - 7680) * 256 + t, aw1, ab1, aw2, ab2, awo, abo, rate_out);
    } else if (ab < 8160) {
        arm_body<128, 192, OFF3>(flat_q, (ab - 8064) * 256 + t, aw1, ab1, aw2, ab2, awo, abo, rate_out);
    } else if (ab < 8184) {
        arm_body<64, 96, OFF4>(flat_q, (ab - 8160) * 256 + t, aw1, ab1, aw2, ab2, awo, abo, rate_out);
    } else if (ab < 8190) {
        arm_body<32, 48, OFF5>(flat_q, (ab - 8184) * 256 + t, aw1, ab1, aw2, ab2, awo, abo, rate_out);
    } else {
        arm_body<16, 24, OFF6>(flat_q, (ab - 8190) * 256 + t, aw1, ab1, aw2, ab2, awo, abo, rate_out);
    }
}

// ---------------- launch ----------------
extern "C" void kernel_launch(void* const* d_in, const int* in_sizes, int n_in,
                              void* d_out, int out_size, void* d_ws, size_t ws_size,
                              hipStream_t stream) {
    const float* lat[7];
    for (int i = 0; i < 7; i++) lat[i] = (const float*)d_in[i];
    const float* noise  = (const float*)d_in[7];
    const float* arm_w1 = (const float*)d_in[8];
    const float* arm_b1 = (const float*)d_in[9];
    const float* arm_w2 = (const float*)d_in[10];
    const float* arm_b2 = (const float*)d_in[11];
    const float* arm_wo = (const float*)d_in[12];
    const float* arm_bo = (const float*)d_in[13];
    const float* ups_k  = (const float*)d_in[14]; // (6,8)
    const float* pre_k  = (const float*)d_in[15]; // (6,7)
    const float* syn_w1 = (const float*)d_in[16]; // (48,7)
    const float* syn_b1 = (const float*)d_in[17];
    const float* syn_w2 = (const float*)d_in[18]; // (6,48)
    const float* syn_b2 = (const float*)d_in[19];
    float* out = (float*)d_out;

    float* flat_q = (float*)d_ws;                 // N_TOTAL
    float* bufA   = flat_q + N_TOTAL;             // up to 6*512*768
    float* bufB   = bufA + 6 * 512 * 768;         // up to 5*256*384

    static const int SH[7]  = {1024, 512, 256, 128, 64, 32, 16};
    static const int SW[7]  = {1536, 768, 384, 192, 96, 48, 24};
    static const int OFF[7] = {OFF0, OFF1, OFF2, OFF3, OFF4, OFF5, OFF6};

    // 1. quantization
    quant_kernel<<<(N_TOTAL + 255) / 256, 256, 0, stream>>>(
        lat[0], lat[1], lat[2], lat[3], lat[4], lat[5], lat[6], noise, flat_q);

    // 2. intermediate pyramid steps s=0..4 (quad kernels), ping-pong bufA/bufB
    const float* xin = flat_q + OFF6; // dec[6], 1ch 16x24
    float* bufs[2] = {bufA, bufB};
    for (int s = 0; s < 5; s++) {
        int i    = 6 - s;
        int hin  = SH[i], win_ = SW[i];
        int hout = SH[i - 1], wout = SW[i - 1];
        int cin  = s + 1;
        float* xout = bufs[s & 1];
        dim3 blk(16, 16);
        dim3 grd((wout / 2 + 15) / 16, (hout / 2 + 15) / 16, cin + 1);
        pyramid_quad_kernel<<<grd, blk, 0, stream>>>(xin, hin, win_,
                                                     flat_q + OFF[i - 1],
                                                     ups_k + s * 8, pre_k + s * 7,
                                                     xout, hout, wout);
        xin = xout;
    }

    // 3. mega kernel: fused final pyramid step + synthesis, co-scheduled with ARM+rate
    mega_kernel<<<9728, 256, 0, stream>>>(bufA, flat_q,
                                          ups_k + 5 * 8, pre_k + 5 * 7,
                                          syn_w1, syn_b1, syn_w2, syn_b2,
                                          arm_w1, arm_b1, arm_w2, arm_b2,
                                          arm_wo, arm_bo, out);
}